// Round 5
// baseline (482.689 us; speedup 1.0000x reference)
//
#include <hip/hip_runtime.h>
#include <hip/hip_bf16.h>
#include <math.h>

#define B_ 4
#define N_ 8192
#define K_ 16
#define BN_ (B_ * N_)
#define EPS_ 1e-5f

#define S_ 8              // candidate splits = waves per block
#define TPB (S_ * 64)     // 512 threads
#define QPB 64            // queries per block (one per lane)
#define MCAND (N_ / S_)   // 1024 candidates per wave
#define DEPTH 16          // deferred-insert buffer depth per lane
#define RPB 128           // rows per block in MLP kernels

// ---------------- pack coords (B*N,3) -> float4 ----------------
__global__ __launch_bounds__(256) void pack_coords(const float* __restrict__ coords,
                                                   float4* __restrict__ out) {
    int i = blockIdx.x * 256 + threadIdx.x;
    if (i >= BN_) return;
    out[i] = make_float4(coords[3 * i], coords[3 * i + 1], coords[3 * i + 2], 0.0f);
}

// ---------------- exact 16-NN: scalar-broadcast candidates, deferred insertion,
// cross-wave shared pruning threshold ----------------
// One query per lane; wave w scans a contiguous candidate slice with wave-uniform
// addresses (s_load broadcast). Waves serving the same query (same lane id) share
// a pruning threshold via LDS: each publishes its 16th-best distance; pruning a
// candidate >= another wave's 16th-best is exact (that wave holds 16 closer ones).
// Passing candidates push packed (d2,idx) into a per-lane LDS column; the 16-deep
// register insertion runs only on (rare) flushes. 3-round LDS tree merge at end.
__global__ __launch_bounds__(512) void knn_kernel(const float4* __restrict__ coords4,
                                                  int* __restrict__ idxOut) {
    __shared__ float2 bufp[DEPTH][TPB];       // 64 KB
    __shared__ float thr2d[S_][64];           // 2 KB shared thresholds

    const int bpb = N_ / QPB;                 // 128 blocks per batch
    int b = blockIdx.x / bpb;
    int qbase = (blockIdx.x % bpb) * QPB;
    int t = threadIdx.x;
    int lane = t & 63;
    int w = __builtin_amdgcn_readfirstlane(t >> 6);   // wave-uniform split id -> SGPR
    int q = qbase + lane;

    thr2d[t >> 6][lane] = 3.4e38f;
    __syncthreads();

    const float4* cb = coords4 + (size_t)b * N_;
    float4 qc = cb[q];
    float qx = qc.x, qy = qc.y, qz = qc.z;

    float key[K_];
    int   id[K_];
#pragma unroll
    for (int j = 0; j < K_; j++) { key[j] = 3.4e38f; id[j] = -1; }

    int cnt = 0;
    float bound = 3.4e38f;
    float lim = 3.4e38f;                      // = min(key[15], bound)

    auto flush = [&]() {
        for (int j = 0; j < cnt; ++j) {
            float2 e = bufp[j][t];
            float d2 = e.x;
            int   m  = __float_as_int(e.y);
            if (d2 < key[K_ - 1]) {
#pragma unroll
                for (int jj = K_ - 1; jj > 0; --jj) {
                    bool up = d2 < key[jj - 1];
                    float ik = fminf(d2, key[jj]);
                    int   ii = (d2 < key[jj]) ? m : id[jj];
                    key[jj] = up ? key[jj - 1] : ik;
                    id[jj]  = up ? id[jj - 1]  : ii;
                }
                if (d2 < key[0]) { key[0] = d2; id[0] = m; }
            }
        }
        cnt = 0;
    };

    auto proc = [&](float4 c, int m) {
        float dx = qx - c.x, dy = qy - c.y, dz = qz - c.z;
        float d2 = dx * dx;
        d2 = fmaf(dy, dy, d2);
        d2 = fmaf(dz, dz, d2);
        if (d2 < lim) {
            bufp[cnt][t] = make_float2(d2, __int_as_float(m));
            cnt++;
        }
    };

    const int base = w * MCAND;
    for (int i = 0; i < MCAND; i += 8) {
        // wave-uniform addresses -> scalar loads (SMEM broadcast)
        float4 c0 = cb[base + i + 0];
        float4 c1 = cb[base + i + 1];
        float4 c2 = cb[base + i + 2];
        float4 c3 = cb[base + i + 3];
        float4 c4 = cb[base + i + 4];
        float4 c5 = cb[base + i + 5];
        float4 c6 = cb[base + i + 6];
        float4 c7 = cb[base + i + 7];
        proc(c0, base + i + 0);
        proc(c1, base + i + 1);
        proc(c2, base + i + 2);
        proc(c3, base + i + 3);
        proc(c4, base + i + 4);
        proc(c5, base + i + 5);
        proc(c6, base + i + 6);
        proc(c7, base + i + 7);
        // each lane pushed at most 8 since last check; DEPTH-7 guard => no overflow
        if (__any(cnt >= DEPTH - 7)) {
            flush();
            lim = fminf(key[K_ - 1], bound);
        }
        if ((i & 56) == 56) {                 // every 64 candidates: publish + refresh
            thr2d[w][lane] = key[K_ - 1];
            float m0 = fminf(thr2d[0][lane], thr2d[1][lane]);
            float m1 = fminf(thr2d[2][lane], thr2d[3][lane]);
            float m2 = fminf(thr2d[4][lane], thr2d[5][lane]);
            float m3 = fminf(thr2d[6][lane], thr2d[7][lane]);
            bound = fminf(fminf(m0, m1), fminf(m2, m3));
            lim = fminf(key[K_ - 1], bound);
        }
    }
    flush();

    // publish this lane's sorted 16-list into its LDS column
#pragma unroll
    for (int j = 0; j < K_; j++) bufp[j][t] = make_float2(key[j], __int_as_float(id[j]));

    // tree merge: 8 lists -> 4 -> 2 -> 1 (partner waves at stride step*64)
    int* op = idxOut + ((size_t)b * N_ + q) * K_;
    for (int step = 1; step < S_; step <<= 1) {
        bool active = (w & (2 * step - 1)) == 0;
        float md[K_];
        int   mi[K_];
        __syncthreads();
        if (active) {
            int pa = t, pb = t + step * 64;
            int ia = 0, ib = 0;
#pragma unroll
            for (int r = 0; r < K_; ++r) {
                float2 ea = bufp[ia][pa];
                float2 eb = bufp[ib][pb];
                bool sel = ea.x <= eb.x;
                md[r] = sel ? ea.x : eb.x;
                mi[r] = __float_as_int(sel ? ea.y : eb.y);
                ia += sel ? 1 : 0;
                ib += sel ? 0 : 1;
            }
        }
        __syncthreads();
        if (active) {
            if (step == S_ / 2) {
#pragma unroll
                for (int r = 0; r < K_; ++r) op[r] = mi[r];
            } else {
#pragma unroll
                for (int r = 0; r < K_; ++r) bufp[r][t] = make_float2(md[r], __int_as_float(mi[r]));
            }
        }
    }
}

// ---------------- fused: gather-mean + mm1 + stat partial ----------------
// 128 threads/block, one row per thread, 256 blocks. Stats via LDS y-stage,
// fixed-order per-wave column sums (deterministic).
__global__ __launch_bounds__(128) void gmm1_kernel(const float* __restrict__ feats,
                                                   const int* __restrict__ idx,
                                                   const float* __restrict__ W1,
                                                   const float* __restrict__ b1,
                                                   float* __restrict__ Y1,
                                                   float* __restrict__ part) {
    __shared__ float Ws[64 * 64];             // 16 KB
    __shared__ float ybuf[RPB][64];           // 32 KB
    int t = threadIdx.x;
    for (int i = t; i < 64 * 64; i += 128) Ws[i] = W1[i];
    __syncthreads();

    int r = blockIdx.x * RPB + t;
    int b = r >> 13;
    const float* fb = feats + ((size_t)b * N_) * 64;
    const int* ip = idx + (size_t)r * K_;

    float x[64];
#pragma unroll
    for (int j = 0; j < 64; j++) x[j] = 0.0f;
#pragma unroll
    for (int j = 0; j < K_; j++) {
        const float4* np = (const float4*)(fb + (size_t)ip[j] * 64);
#pragma unroll
        for (int i4 = 0; i4 < 16; i4++) {
            float4 v = np[i4];
            x[4 * i4]     += v.x;
            x[4 * i4 + 1] += v.y;
            x[4 * i4 + 2] += v.z;
            x[4 * i4 + 3] += v.w;
        }
    }
#pragma unroll
    for (int j = 0; j < 64; j++) x[j] *= (1.0f / 16.0f);

    float acc[64];
#pragma unroll
    for (int j = 0; j < 64; j++) acc[j] = b1[j];
#pragma unroll
    for (int c = 0; c < 64; c++) {
        float xv = x[c];
#pragma unroll
        for (int jj = 0; jj < 16; jj++) {
            float4 w4 = *(const float4*)&Ws[c * 64 + 4 * jj];
            acc[4 * jj]     = fmaf(xv, w4.x, acc[4 * jj]);
            acc[4 * jj + 1] = fmaf(xv, w4.y, acc[4 * jj + 1]);
            acc[4 * jj + 2] = fmaf(xv, w4.z, acc[4 * jj + 2]);
            acc[4 * jj + 3] = fmaf(xv, w4.w, acc[4 * jj + 3]);
        }
    }
    float4* yp = (float4*)(Y1 + (size_t)r * 64);
#pragma unroll
    for (int i = 0; i < 16; i++) {
        float4 v = make_float4(acc[4 * i], acc[4 * i + 1], acc[4 * i + 2], acc[4 * i + 3]);
        yp[i] = v;
        *(float4*)&ybuf[t][4 * i] = v;
    }
    __syncthreads();
    // per-channel partials: wave0 = sums, wave1 = sumsq (fixed serial order)
    int c = t & 63;
    float s = 0.0f;
    if (t < 64) {
        for (int r2 = 0; r2 < RPB; ++r2) s += ybuf[r2][c];
    } else {
        for (int r2 = 0; r2 < RPB; ++r2) { float v = ybuf[r2][c]; s = fmaf(v, v, s); }
    }
    part[(size_t)blockIdx.x * 128 + t] = s;
}

// ---------------- stage 2: reduce stats1, bn+relu, mm(Wa), stat partial ----------------
__global__ __launch_bounds__(128) void mm2_kernel(const float* __restrict__ Y1,
                                                  const float* __restrict__ Wa,
                                                  const float* __restrict__ ba,
                                                  const float* __restrict__ g1,
                                                  const float* __restrict__ be1,
                                                  const float* __restrict__ part1,
                                                  float* __restrict__ X1,
                                                  float* __restrict__ Y2,
                                                  float* __restrict__ part2) {
    __shared__ float Ws[64 * 64];
    __shared__ float ybuf[RPB][64];
    __shared__ float red[128];
    __shared__ float sc[64], sh[64];
    int t = threadIdx.x;
    for (int i = t; i < 64 * 64; i += 128) Ws[i] = Wa[i];
    {
        float s = 0.0f;
#pragma unroll 8
        for (int g = 0; g < 256; ++g) s += part1[(size_t)g * 128 + t];
        red[t] = s;
    }
    __syncthreads();
    if (t < 64) {
        float mean = red[t] * (1.0f / BN_);
        float var = red[t + 64] * (1.0f / BN_) - mean * mean;
        float rstd = rsqrtf(var + EPS_);
        float scl = rstd * g1[t];
        sc[t] = scl;
        sh[t] = be1[t] - mean * scl;
    }
    __syncthreads();

    int r = blockIdx.x * RPB + t;
    float x[64];
    const float4* xp = (const float4*)(Y1 + (size_t)r * 64);
#pragma unroll
    for (int i = 0; i < 16; i++) {
        float4 v = xp[i];
        x[4 * i]     = fmaxf(0.0f, fmaf(v.x, sc[4 * i],     sh[4 * i]));
        x[4 * i + 1] = fmaxf(0.0f, fmaf(v.y, sc[4 * i + 1], sh[4 * i + 1]));
        x[4 * i + 2] = fmaxf(0.0f, fmaf(v.z, sc[4 * i + 2], sh[4 * i + 2]));
        x[4 * i + 3] = fmaxf(0.0f, fmaf(v.w, sc[4 * i + 3], sh[4 * i + 3]));
    }
    float4* x1p = (float4*)(X1 + (size_t)r * 64);
#pragma unroll
    for (int i = 0; i < 16; i++)
        x1p[i] = make_float4(x[4 * i], x[4 * i + 1], x[4 * i + 2], x[4 * i + 3]);
    float acc[64];
#pragma unroll
    for (int j = 0; j < 64; j++) acc[j] = ba[j];
#pragma unroll
    for (int c = 0; c < 64; c++) {
        float xv = x[c];
#pragma unroll
        for (int jj = 0; jj < 16; jj++) {
            float4 w4 = *(const float4*)&Ws[c * 64 + 4 * jj];
            acc[4 * jj]     = fmaf(xv, w4.x, acc[4 * jj]);
            acc[4 * jj + 1] = fmaf(xv, w4.y, acc[4 * jj + 1]);
            acc[4 * jj + 2] = fmaf(xv, w4.z, acc[4 * jj + 2]);
            acc[4 * jj + 3] = fmaf(xv, w4.w, acc[4 * jj + 3]);
        }
    }
    float4* yp = (float4*)(Y2 + (size_t)r * 64);
#pragma unroll
    for (int i = 0; i < 16; i++) {
        float4 v = make_float4(acc[4 * i], acc[4 * i + 1], acc[4 * i + 2], acc[4 * i + 3]);
        yp[i] = v;
        *(float4*)&ybuf[t][4 * i] = v;
    }
    __syncthreads();
    int c = t & 63;
    float s = 0.0f;
    if (t < 64) {
        for (int r2 = 0; r2 < RPB; ++r2) s += ybuf[r2][c];
    } else {
        for (int r2 = 0; r2 < RPB; ++r2) { float v = ybuf[r2][c]; s = fmaf(v, v, s); }
    }
    part2[(size_t)blockIdx.x * 128 + t] = s;
}

// ---------------- stage 3: reduce stats2, attn=sigmoid(relu(bn2)), fused, mm(W2 64x128) ----------------
__global__ __launch_bounds__(128) void mm3_kernel(const float* __restrict__ Y2,
                                                  const float* __restrict__ X1,
                                                  const float* __restrict__ W2,
                                                  const float* __restrict__ b2,
                                                  const float* __restrict__ ga,
                                                  const float* __restrict__ bea,
                                                  const float* __restrict__ part2,
                                                  float* __restrict__ Y3) {
    __shared__ float Ws[64 * 128];
    __shared__ float red[128];
    __shared__ float sc[64], sh[64];
    int t = threadIdx.x;
    for (int i = t; i < 64 * 128; i += 128) Ws[i] = W2[i];
    {
        float s = 0.0f;
#pragma unroll 8
        for (int g = 0; g < 256; ++g) s += part2[(size_t)g * 128 + t];
        red[t] = s;
    }
    __syncthreads();
    if (t < 64) {
        float mean = red[t] * (1.0f / BN_);
        float var = red[t + 64] * (1.0f / BN_) - mean * mean;
        float rstd = rsqrtf(var + EPS_);
        float scl = rstd * ga[t];
        sc[t] = scl;
        sh[t] = bea[t] - mean * scl;
    }
    __syncthreads();

    int r = blockIdx.x * RPB + t;
    float fx[64];
    const float4* y2p = (const float4*)(Y2 + (size_t)r * 64);
    const float4* x1p = (const float4*)(X1 + (size_t)r * 64);
#pragma unroll
    for (int i = 0; i < 16; i++) {
        float4 v = y2p[i];
        float4 u = x1p[i];
        float t0 = fmaxf(0.0f, fmaf(v.x, sc[4 * i],     sh[4 * i]));
        float t1 = fmaxf(0.0f, fmaf(v.y, sc[4 * i + 1], sh[4 * i + 1]));
        float t2 = fmaxf(0.0f, fmaf(v.z, sc[4 * i + 2], sh[4 * i + 2]));
        float t3 = fmaxf(0.0f, fmaf(v.w, sc[4 * i + 3], sh[4 * i + 3]));
        float a0 = 1.0f / (1.0f + __expf(-t0));
        float a1 = 1.0f / (1.0f + __expf(-t1));
        float a2 = 1.0f / (1.0f + __expf(-t2));
        float a3 = 1.0f / (1.0f + __expf(-t3));
        fx[4 * i]     = u.x * (1.0f + a0);
        fx[4 * i + 1] = u.y * (1.0f + a1);
        fx[4 * i + 2] = u.z * (1.0f + a2);
        fx[4 * i + 3] = u.w * (1.0f + a3);
    }
    float acc[64];
#pragma unroll 1
    for (int h = 0; h < 2; ++h) {
#pragma unroll
        for (int j = 0; j < 64; j++) acc[j] = b2[h * 64 + j];
#pragma unroll
        for (int c = 0; c < 64; c++) {
            float xv = fx[c];
#pragma unroll
            for (int jj = 0; jj < 16; jj++) {
                float4 w4 = *(const float4*)&Ws[c * 128 + h * 64 + 4 * jj];
                acc[4 * jj]     = fmaf(xv, w4.x, acc[4 * jj]);
                acc[4 * jj + 1] = fmaf(xv, w4.y, acc[4 * jj + 1]);
                acc[4 * jj + 2] = fmaf(xv, w4.z, acc[4 * jj + 2]);
                acc[4 * jj + 3] = fmaf(xv, w4.w, acc[4 * jj + 3]);
            }
        }
        float4* yp = (float4*)(Y3 + (size_t)r * 128 + h * 64);
#pragma unroll
        for (int i = 0; i < 16; i++)
            yp[i] = make_float4(acc[4 * i], acc[4 * i + 1], acc[4 * i + 2], acc[4 * i + 3]);
    }
}

// ---------------- per-channel sum/sumsq partials for y3 (deterministic) ----------------
__global__ __launch_bounds__(256) void stat_y3(const float* __restrict__ Y,
                                               float* __restrict__ part) {
    const int C = 128, RP = 2;
    int c = threadIdx.x & (C - 1);
    int rs = threadIdx.x / C;
    float s1 = 0.0f, s2 = 0.0f;
    for (int r = blockIdx.x * RP + rs; r < BN_; r += gridDim.x * RP) {
        float v = Y[(size_t)r * C + c];
        s1 += v;
        s2 = fmaf(v, v, s2);
    }
    __shared__ float l1[256], l2[256];
    l1[threadIdx.x] = s1; l2[threadIdx.x] = s2;
    __syncthreads();
    if (threadIdx.x < C) {
        s1 += l1[threadIdx.x + C];
        s2 += l2[threadIdx.x + C];
        part[(size_t)blockIdx.x * 256 + c] = s1;
        part[(size_t)blockIdx.x * 256 + C + c] = s2;
    }
}

// ---------------- final: out = relu(bn3(y3)) in-place, grid-stride ----------------
__global__ __launch_bounds__(256) void bn_final(float* __restrict__ Y3,
                                                const float* __restrict__ g2,
                                                const float* __restrict__ be2,
                                                const float* __restrict__ part) {
    __shared__ float red[256];
    __shared__ float sc[128], sh[128];
    int t = threadIdx.x;
    {
        float s = 0.0f;
#pragma unroll 8
        for (int g = 0; g < 256; ++g) s += part[(size_t)g * 256 + t];
        red[t] = s;
    }
    __syncthreads();
    if (t < 128) {
        float mean = red[t] * (1.0f / BN_);
        float var = red[t + 128] * (1.0f / BN_) - mean * mean;
        float rstd = rsqrtf(var + EPS_);
        float scl = rstd * g2[t];
        sc[t] = scl;
        sh[t] = be2[t] - mean * scl;
    }
    __syncthreads();
    const int total = BN_ * 128 / 4;
    float4* p = (float4*)Y3;
    for (int i = blockIdx.x * 256 + t; i < total; i += 256 * 256) {
        float4 v = p[i];
        int c0 = (i * 4) & 127;
        v.x = fmaxf(0.0f, fmaf(v.x, sc[c0],     sh[c0]));
        v.y = fmaxf(0.0f, fmaf(v.y, sc[c0 + 1], sh[c0 + 1]));
        v.z = fmaxf(0.0f, fmaf(v.z, sc[c0 + 2], sh[c0 + 2]));
        v.w = fmaxf(0.0f, fmaf(v.w, sc[c0 + 3], sh[c0 + 3]));
        p[i] = v;
    }
}

extern "C" void kernel_launch(void* const* d_in, const int* in_sizes, int n_in,
                              void* d_out, int out_size, void* d_ws, size_t ws_size,
                              hipStream_t stream) {
    const float* coords = (const float*)d_in[0];
    const float* feats  = (const float*)d_in[1];
    const float* W1  = (const float*)d_in[3];
    const float* b1  = (const float*)d_in[4];
    const float* g1  = (const float*)d_in[5];
    const float* be1 = (const float*)d_in[6];
    const float* Wa  = (const float*)d_in[7];
    const float* ba  = (const float*)d_in[8];
    const float* ga  = (const float*)d_in[9];
    const float* bea = (const float*)d_in[10];
    const float* W2  = (const float*)d_in[11];
    const float* b2  = (const float*)d_in[12];
    const float* g2  = (const float*)d_in[13];
    const float* be2 = (const float*)d_in[14];

    float* ws = (float*)d_ws;
    float4* coords4 = (float4*)ws;                         // 131072 floats
    int*    idxbuf  = (int*)(ws + 131072);                 // BN_*16 ints
    float*  y1 = ws + 131072 + 524288;                     // BN_*64
    float*  x1 = y1 + (size_t)BN_ * 64;
    float*  y2 = x1 + (size_t)BN_ * 64;
    float*  part1 = y2 + (size_t)BN_ * 64;                 // 256*128
    float*  part2 = part1 + 256 * 128;                     // 256*128
    float*  part3 = part2 + 256 * 128;                     // 256*256
    float*  y3 = (float*)d_out;                            // BN_*128 lives in d_out

    pack_coords<<<(BN_ + 255) / 256, 256, 0, stream>>>(coords, coords4);
    knn_kernel<<<B_ * (N_ / QPB), TPB, 0, stream>>>(coords4, idxbuf);

    gmm1_kernel<<<BN_ / RPB, 128, 0, stream>>>(feats, idxbuf, W1, b1, y1, part1);
    mm2_kernel<<<BN_ / RPB, 128, 0, stream>>>(y1, Wa, ba, g1, be1, part1, x1, y2, part2);
    mm3_kernel<<<BN_ / RPB, 128, 0, stream>>>(y2, x1, W2, b2, ga, bea, part2, y3);
    stat_y3<<<256, 256, 0, stream>>>(y3, part3);
    bn_final<<<256, 256, 0, stream>>>(y3, g2, be2, part3);
}

// Round 6
// 441.185 us; speedup vs baseline: 1.0941x; 1.0941x over previous
//
#include <hip/hip_runtime.h>
#include <hip/hip_bf16.h>
#include <math.h>

#define B_ 4
#define N_ 8192
#define K_ 16
#define BN_ (B_ * N_)
#define EPS_ 1e-5f

#define S_ 8              // candidate splits = waves per block
#define TPB (S_ * 64)     // 512 threads
#define QPB 64            // queries per block (one per lane)
#define MCAND (N_ / S_)   // 1024 candidates per wave
#define DEPTH 16          // deferred-insert buffer depth per lane

#define NBLK 256          // persistent tail blocks (1/CU -> co-residency guaranteed)
#define ROWS 128          // rows per tail block (2 threads/row)

// ---------------- pack coords (B*N,3) -> float4 ----------------
__global__ __launch_bounds__(256) void pack_coords(const float* __restrict__ coords,
                                                   float4* __restrict__ out) {
    int i = blockIdx.x * 256 + threadIdx.x;
    if (i >= BN_) return;
    out[i] = make_float4(coords[3 * i], coords[3 * i + 1], coords[3 * i + 2], 0.0f);
}

// ---------------- exact 16-NN (unchanged from round 5) ----------------
__global__ __launch_bounds__(512) void knn_kernel(const float4* __restrict__ coords4,
                                                  int* __restrict__ idxOut) {
    __shared__ float2 bufp[DEPTH][TPB];       // 64 KB
    __shared__ float thr2d[S_][64];           // 2 KB shared thresholds

    const int bpb = N_ / QPB;                 // 128 blocks per batch
    int b = blockIdx.x / bpb;
    int qbase = (blockIdx.x % bpb) * QPB;
    int t = threadIdx.x;
    int lane = t & 63;
    int w = __builtin_amdgcn_readfirstlane(t >> 6);
    int q = qbase + lane;

    thr2d[t >> 6][lane] = 3.4e38f;
    __syncthreads();

    const float4* cb = coords4 + (size_t)b * N_;
    float4 qc = cb[q];
    float qx = qc.x, qy = qc.y, qz = qc.z;

    float key[K_];
    int   id[K_];
#pragma unroll
    for (int j = 0; j < K_; j++) { key[j] = 3.4e38f; id[j] = -1; }

    int cnt = 0;
    float bound = 3.4e38f;
    float lim = 3.4e38f;

    auto flush = [&]() {
        for (int j = 0; j < cnt; ++j) {
            float2 e = bufp[j][t];
            float d2 = e.x;
            int   m  = __float_as_int(e.y);
            if (d2 < key[K_ - 1]) {
#pragma unroll
                for (int jj = K_ - 1; jj > 0; --jj) {
                    bool up = d2 < key[jj - 1];
                    float ik = fminf(d2, key[jj]);
                    int   ii = (d2 < key[jj]) ? m : id[jj];
                    key[jj] = up ? key[jj - 1] : ik;
                    id[jj]  = up ? id[jj - 1]  : ii;
                }
                if (d2 < key[0]) { key[0] = d2; id[0] = m; }
            }
        }
        cnt = 0;
    };

    auto proc = [&](float4 c, int m) {
        float dx = qx - c.x, dy = qy - c.y, dz = qz - c.z;
        float d2 = dx * dx;
        d2 = fmaf(dy, dy, d2);
        d2 = fmaf(dz, dz, d2);
        if (d2 < lim) {
            bufp[cnt][t] = make_float2(d2, __int_as_float(m));
            cnt++;
        }
    };

    const int base = w * MCAND;
    for (int i = 0; i < MCAND; i += 8) {
        float4 c0 = cb[base + i + 0];
        float4 c1 = cb[base + i + 1];
        float4 c2 = cb[base + i + 2];
        float4 c3 = cb[base + i + 3];
        float4 c4 = cb[base + i + 4];
        float4 c5 = cb[base + i + 5];
        float4 c6 = cb[base + i + 6];
        float4 c7 = cb[base + i + 7];
        proc(c0, base + i + 0);
        proc(c1, base + i + 1);
        proc(c2, base + i + 2);
        proc(c3, base + i + 3);
        proc(c4, base + i + 4);
        proc(c5, base + i + 5);
        proc(c6, base + i + 6);
        proc(c7, base + i + 7);
        if (__any(cnt >= DEPTH - 7)) {
            flush();
            lim = fminf(key[K_ - 1], bound);
        }
        if ((i & 56) == 56) {
            thr2d[w][lane] = key[K_ - 1];
            float m0 = fminf(thr2d[0][lane], thr2d[1][lane]);
            float m1 = fminf(thr2d[2][lane], thr2d[3][lane]);
            float m2 = fminf(thr2d[4][lane], thr2d[5][lane]);
            float m3 = fminf(thr2d[6][lane], thr2d[7][lane]);
            bound = fminf(fminf(m0, m1), fminf(m2, m3));
            lim = fminf(key[K_ - 1], bound);
        }
    }
    flush();

#pragma unroll
    for (int j = 0; j < K_; j++) bufp[j][t] = make_float2(key[j], __int_as_float(id[j]));

    int* op = idxOut + ((size_t)b * N_ + q) * K_;
    for (int step = 1; step < S_; step <<= 1) {
        bool active = (w & (2 * step - 1)) == 0;
        float md[K_];
        int   mi[K_];
        __syncthreads();
        if (active) {
            int pa = t, pb = t + step * 64;
            int ia = 0, ib = 0;
#pragma unroll
            for (int r = 0; r < K_; ++r) {
                float2 ea = bufp[ia][pa];
                float2 eb = bufp[ib][pb];
                bool sel = ea.x <= eb.x;
                md[r] = sel ? ea.x : eb.x;
                mi[r] = __float_as_int(sel ? ea.y : eb.y);
                ia += sel ? 1 : 0;
                ib += sel ? 0 : 1;
            }
        }
        __syncthreads();
        if (active) {
            if (step == S_ / 2) {
#pragma unroll
                for (int r = 0; r < K_; ++r) op[r] = mi[r];
            } else {
#pragma unroll
                for (int r = 0; r < K_; ++r) bufp[r][t] = make_float2(md[r], __int_as_float(mi[r]));
            }
        }
    }
}

// ---------------- device-scope grid barrier (persistent kernel) ----------------
// counter zeroed each launch via hipMemsetAsync; monotone targets -> no reset race.
__device__ __forceinline__ void gridbar(int* cnt, int target) {
    __syncthreads();
    if (threadIdx.x == 0) {
        __threadfence();
        atomicAdd(cnt, 1);
        while (__hip_atomic_load(cnt, __ATOMIC_RELAXED, __HIP_MEMORY_SCOPE_AGENT) < target)
            __builtin_amdgcn_s_sleep(2);
        __threadfence();
    }
    __syncthreads();
}

// ---------------- persistent fused tail: gather+mm1+bn1+mm2+bn2(att)+mm3+bn3 ----------------
// 256 blocks x 256 threads; 2 threads/row (h = half), 128 rows/block.
// All intermediates in regs + one LDS row buffer; only y3 touches HBM.
__global__ __launch_bounds__(256, 2) void fused_tail(
        const float* __restrict__ feats, const int* __restrict__ idx,
        const float* __restrict__ W1, const float* __restrict__ b1,
        const float* __restrict__ g1, const float* __restrict__ be1,
        const float* __restrict__ Wa, const float* __restrict__ ba,
        const float* __restrict__ ga, const float* __restrict__ bea,
        const float* __restrict__ W2, const float* __restrict__ b2,
        const float* __restrict__ g2, const float* __restrict__ be2,
        float* __restrict__ out,
        float* __restrict__ part1, float* __restrict__ part2, float* __restrict__ part3,
        int* __restrict__ barcnt) {
    __shared__ float buf[ROWS][68];    // 34.8 KB row-stage (x0 -> y1 -> x1 -> y2 -> fx -> y3 halves)
    __shared__ float Ws[64 * 128];     // 32 KB weight stage
    __shared__ float red[256];
    __shared__ float scs[128], shs[128];

    int t = threadIdx.x;
    int rl = t >> 1;                   // local row 0..127
    int h = t & 1;                     // half: channels [h*32, h*32+32) (mm3: [h*64, h*64+64))
    int row = blockIdx.x * ROWS + rl;
    int b = row >> 13;

    // stage W1
    for (int i = t; i < 64 * 64; i += 256) Ws[i] = W1[i];

    // ---- gather + mean: this thread's 32 channels
    const float* fb = feats + ((size_t)b << 13) * 64;
    const int* ip = idx + (size_t)row * K_;
    float xh[32];
#pragma unroll
    for (int j = 0; j < 32; j++) xh[j] = 0.0f;
#pragma unroll
    for (int j = 0; j < K_; j++) {
        const float4* np = (const float4*)(fb + (size_t)ip[j] * 64 + h * 32);
#pragma unroll
        for (int f = 0; f < 8; f++) {
            float4 v = np[f];
            xh[4 * f] += v.x; xh[4 * f + 1] += v.y; xh[4 * f + 2] += v.z; xh[4 * f + 3] += v.w;
        }
    }
#pragma unroll
    for (int j = 0; j < 32; j++) xh[j] *= (1.0f / 16.0f);

    __syncthreads();                   // Ws ready, buf free
#pragma unroll
    for (int f = 0; f < 8; f++)
        *(float4*)&buf[rl][h * 32 + 4 * f] = make_float4(xh[4 * f], xh[4 * f + 1], xh[4 * f + 2], xh[4 * f + 3]);
    __syncthreads();

    float x[64];
#pragma unroll
    for (int f = 0; f < 16; f++) *(float4*)&x[4 * f] = *(const float4*)&buf[rl][4 * f];

    // ---- mm1: y1 half
    float acc[32];
#pragma unroll
    for (int j = 0; j < 32; j++) acc[j] = b1[h * 32 + j];
#pragma unroll
    for (int c = 0; c < 64; c++) {
        float xv = x[c];
#pragma unroll
        for (int f = 0; f < 8; f++) {
            float4 w4 = *(const float4*)&Ws[c * 64 + h * 32 + 4 * f];
            acc[4 * f]     = fmaf(xv, w4.x, acc[4 * f]);
            acc[4 * f + 1] = fmaf(xv, w4.y, acc[4 * f + 1]);
            acc[4 * f + 2] = fmaf(xv, w4.z, acc[4 * f + 2]);
            acc[4 * f + 3] = fmaf(xv, w4.w, acc[4 * f + 3]);
        }
    }

    // ---- stage y1, stats partials
    __syncthreads();
#pragma unroll
    for (int f = 0; f < 8; f++)
        *(float4*)&buf[rl][h * 32 + 4 * f] = make_float4(acc[4 * f], acc[4 * f + 1], acc[4 * f + 2], acc[4 * f + 3]);
    for (int i = t; i < 64 * 64; i += 256) Ws[i] = Wa[i];   // preload Wa (mm1 reads done)
    __syncthreads();
    if (t < 128) {
        int c = t & 63;
        float s = 0.0f;
        if (t < 64) { for (int r = 0; r < ROWS; ++r) s += buf[r][c]; }
        else        { for (int r = 0; r < ROWS; ++r) { float v = buf[r][c]; s = fmaf(v, v, s); } }
        part1[blockIdx.x * 128 + t] = s;
    }
    gridbar(barcnt, NBLK);

    // ---- reduce stats1 (redundant per block)
    if (t < 128) {
        float s = 0.0f;
#pragma unroll 8
        for (int g = 0; g < NBLK; ++g) s += part1[g * 128 + t];
        red[t] = s;
    }
    __syncthreads();
    if (t < 64) {
        float mean = red[t] * (1.0f / BN_);
        float var = red[t + 64] * (1.0f / BN_) - mean * mean;
        float rstd = rsqrtf(var + EPS_);
        float scl = rstd * g1[t];
        scs[t] = scl;
        shs[t] = be1[t] - mean * scl;
    }
    __syncthreads();

    // ---- x1 half = relu(bn1(y1)), stage full x1
#pragma unroll
    for (int j = 0; j < 32; j++)
        acc[j] = fmaxf(0.0f, fmaf(acc[j], scs[h * 32 + j], shs[h * 32 + j]));
#pragma unroll
    for (int f = 0; f < 8; f++)
        *(float4*)&buf[rl][h * 32 + 4 * f] = make_float4(acc[4 * f], acc[4 * f + 1], acc[4 * f + 2], acc[4 * f + 3]);
    __syncthreads();
#pragma unroll
    for (int f = 0; f < 16; f++) *(float4*)&x[4 * f] = *(const float4*)&buf[rl][4 * f];

    // ---- mm2: y2 half (x = full x1 row; Ws = Wa)
#pragma unroll
    for (int j = 0; j < 32; j++) acc[j] = ba[h * 32 + j];
#pragma unroll
    for (int c = 0; c < 64; c++) {
        float xv = x[c];
#pragma unroll
        for (int f = 0; f < 8; f++) {
            float4 w4 = *(const float4*)&Ws[c * 64 + h * 32 + 4 * f];
            acc[4 * f]     = fmaf(xv, w4.x, acc[4 * f]);
            acc[4 * f + 1] = fmaf(xv, w4.y, acc[4 * f + 1]);
            acc[4 * f + 2] = fmaf(xv, w4.z, acc[4 * f + 2]);
            acc[4 * f + 3] = fmaf(xv, w4.w, acc[4 * f + 3]);
        }
    }

    // ---- stage y2, stats partials; preload W2 (full 64x128)
    __syncthreads();
#pragma unroll
    for (int f = 0; f < 8; f++)
        *(float4*)&buf[rl][h * 32 + 4 * f] = make_float4(acc[4 * f], acc[4 * f + 1], acc[4 * f + 2], acc[4 * f + 3]);
    for (int i = t; i < 64 * 128; i += 256) Ws[i] = W2[i];
    __syncthreads();
    if (t < 128) {
        int c = t & 63;
        float s = 0.0f;
        if (t < 64) { for (int r = 0; r < ROWS; ++r) s += buf[r][c]; }
        else        { for (int r = 0; r < ROWS; ++r) { float v = buf[r][c]; s = fmaf(v, v, s); } }
        part2[blockIdx.x * 128 + t] = s;
    }
    gridbar(barcnt, 2 * NBLK);

    if (t < 128) {
        float s = 0.0f;
#pragma unroll 8
        for (int g = 0; g < NBLK; ++g) s += part2[g * 128 + t];
        red[t] = s;
    }
    __syncthreads();
    if (t < 64) {
        float mean = red[t] * (1.0f / BN_);
        float var = red[t + 64] * (1.0f / BN_) - mean * mean;
        float rstd = rsqrtf(var + EPS_);
        float scl = rstd * ga[t];
        scs[t] = scl;
        shs[t] = bea[t] - mean * scl;
    }
    __syncthreads();

    // ---- fx half = x1 * (1 + sigmoid(relu(bn2(y2)))); stage full fx
#pragma unroll
    for (int j = 0; j < 32; j++) {
        float tv = fmaxf(0.0f, fmaf(acc[j], scs[h * 32 + j], shs[h * 32 + j]));
        float a = 1.0f / (1.0f + __expf(-tv));
        acc[j] = x[h * 32 + j] * (1.0f + a);
    }
#pragma unroll
    for (int f = 0; f < 8; f++)
        *(float4*)&buf[rl][h * 32 + 4 * f] = make_float4(acc[4 * f], acc[4 * f + 1], acc[4 * f + 2], acc[4 * f + 3]);
    __syncthreads();
#pragma unroll
    for (int f = 0; f < 16; f++) *(float4*)&x[4 * f] = *(const float4*)&buf[rl][4 * f];

    // ---- mm3: y3 half (64 outputs per thread), write unnormalized y3 to out
    float acc64[64];
#pragma unroll
    for (int j = 0; j < 64; j++) acc64[j] = b2[h * 64 + j];
#pragma unroll
    for (int c = 0; c < 64; c++) {
        float xv = x[c];
#pragma unroll
        for (int f = 0; f < 16; f++) {
            float4 w4 = *(const float4*)&Ws[c * 128 + h * 64 + 4 * f];
            acc64[4 * f]     = fmaf(xv, w4.x, acc64[4 * f]);
            acc64[4 * f + 1] = fmaf(xv, w4.y, acc64[4 * f + 1]);
            acc64[4 * f + 2] = fmaf(xv, w4.z, acc64[4 * f + 2]);
            acc64[4 * f + 3] = fmaf(xv, w4.w, acc64[4 * f + 3]);
        }
    }
    float4* op = (float4*)(out + (size_t)row * 128 + h * 64);
#pragma unroll
    for (int f = 0; f < 16; f++)
        op[f] = make_float4(acc64[4 * f], acc64[4 * f + 1], acc64[4 * f + 2], acc64[4 * f + 3]);

    // ---- y3 stats in two passes (channels 0-63 from h==0 threads, 64-127 from h==1)
    __syncthreads();
    if (h == 0) {
#pragma unroll
        for (int f = 0; f < 16; f++)
            *(float4*)&buf[rl][4 * f] = make_float4(acc64[4 * f], acc64[4 * f + 1], acc64[4 * f + 2], acc64[4 * f + 3]);
    }
    __syncthreads();
    if (t < 128) {
        int c = t & 63;
        float s = 0.0f;
        if (t < 64) { for (int r = 0; r < ROWS; ++r) s += buf[r][c]; }
        else        { for (int r = 0; r < ROWS; ++r) { float v = buf[r][c]; s = fmaf(v, v, s); } }
        part3[blockIdx.x * 256 + t] = s;
    }
    __syncthreads();
    if (h == 1) {
#pragma unroll
        for (int f = 0; f < 16; f++)
            *(float4*)&buf[rl][4 * f] = make_float4(acc64[4 * f], acc64[4 * f + 1], acc64[4 * f + 2], acc64[4 * f + 3]);
    }
    __syncthreads();
    if (t < 128) {
        int c = t & 63;
        float s = 0.0f;
        if (t < 64) { for (int r = 0; r < ROWS; ++r) s += buf[r][c]; }
        else        { for (int r = 0; r < ROWS; ++r) { float v = buf[r][c]; s = fmaf(v, v, s); } }
        part3[blockIdx.x * 256 + 128 + t] = s;
    }
    gridbar(barcnt, 3 * NBLK);

    {
        float s = 0.0f;
#pragma unroll 8
        for (int g = 0; g < NBLK; ++g) s += part3[g * 256 + t];
        red[t] = s;
    }
    __syncthreads();
    if (t < 128) {
        int c = t;
        int is = (c < 64) ? c : (64 + c);          // sum slot
        float mean = red[is] * (1.0f / BN_);
        float var = red[is + 64] * (1.0f / BN_) - mean * mean;
        float rstd = rsqrtf(var + EPS_);
        float scl = rstd * g2[c];
        scs[c] = scl;
        shs[c] = be2[c] - mean * scl;
    }
    __syncthreads();

    // ---- final normalize own rows (L2-hot re-read)
#pragma unroll
    for (int f = 0; f < 16; f++) {
        float4 v = op[f];
        int c0 = h * 64 + 4 * f;
        v.x = fmaxf(0.0f, fmaf(v.x, scs[c0],     shs[c0]));
        v.y = fmaxf(0.0f, fmaf(v.y, scs[c0 + 1], shs[c0 + 1]));
        v.z = fmaxf(0.0f, fmaf(v.z, scs[c0 + 2], shs[c0 + 2]));
        v.w = fmaxf(0.0f, fmaf(v.w, scs[c0 + 3], shs[c0 + 3]));
        op[f] = v;
    }
}

extern "C" void kernel_launch(void* const* d_in, const int* in_sizes, int n_in,
                              void* d_out, int out_size, void* d_ws, size_t ws_size,
                              hipStream_t stream) {
    const float* coords = (const float*)d_in[0];
    const float* feats  = (const float*)d_in[1];
    const float* W1  = (const float*)d_in[3];
    const float* b1  = (const float*)d_in[4];
    const float* g1  = (const float*)d_in[5];
    const float* be1 = (const float*)d_in[6];
    const float* Wa  = (const float*)d_in[7];
    const float* ba  = (const float*)d_in[8];
    const float* ga  = (const float*)d_in[9];
    const float* bea = (const float*)d_in[10];
    const float* W2  = (const float*)d_in[11];
    const float* b2  = (const float*)d_in[12];
    const float* g2  = (const float*)d_in[13];
    const float* be2 = (const float*)d_in[14];

    float* ws = (float*)d_ws;
    float4* coords4 = (float4*)ws;                         // 131072 floats
    int*    idxbuf  = (int*)(ws + 131072);                 // BN_*16 ints
    float*  part1 = ws + 131072 + 524288;                  // 256*128
    float*  part2 = part1 + 256 * 128;                     // 256*128
    float*  part3 = part2 + 256 * 128;                     // 256*256
    int*    barcnt = (int*)(part3 + 256 * 256);
    float*  y3 = (float*)d_out;

    hipMemsetAsync(barcnt, 0, 64, stream);
    pack_coords<<<(BN_ + 255) / 256, 256, 0, stream>>>(coords, coords4);
    knn_kernel<<<B_ * (N_ / QPB), TPB, 0, stream>>>(coords4, idxbuf);

    fused_tail<<<NBLK, 256, 0, stream>>>(feats, idxbuf,
                                         W1, b1, g1, be1,
                                         Wa, ba, ga, bea,
                                         W2, b2, g2, be2,
                                         y3, part1, part2, part3, barcnt);
}